// Round 1
// baseline (213.262 us; speedup 1.0000x reference)
//
#include <hip/hip_runtime.h>
#include <cstdint>
#include <cstddef>

constexpr int B_ROWS = 128;
constexpr int N_COLS = 65536;
constexpr int LIST_CAP = 8192;

// ---- ws layout (bytes) ----
constexpr size_t OFF_HISTCNT  = 0;                  // int  [128][2048]  1MB
constexpr size_t OFF_HISTLOSS = (size_t)1 << 20;    // float[128][2048]  1MB
constexpr size_t OFF_NUMPOS   = (size_t)2 << 20;    // int[128]
constexpr size_t OFF_SPOS     = ((size_t)2 << 20) + 512;   // float[128]
constexpr size_t OFF_ROWS     = ((size_t)2 << 20) + 1024;  // double[128]
constexpr size_t OFF_ROWDEN   = ((size_t)2 << 20) + 2048;  // int[128]
constexpr size_t ZERO_BYTES   = ((size_t)2 << 20) + 4096;
constexpr size_t OFF_KEYS     = (size_t)4 << 20;    // uint[128*65536] 32MB (optional)

// ---- monotone key <-> pred ----
__device__ __forceinline__ unsigned key_from_pred(float x) {
  unsigned b = __float_as_uint(x);
  return (b & 0x80000000u) ? ~b : (b | 0x80000000u);
}
__device__ __forceinline__ float pred_from_key(unsigned k) {
  unsigned b = (k & 0x80000000u) ? (k ^ 0x80000000u) : ~k;
  return __uint_as_float(b);
}

// ---- elementwise losses (match reference op order; gamma=2, alpha=0.75, w=3) ----
__device__ __forceinline__ float neg_loss(float x) {
  float ax = fabsf(x);
  float e  = expf(-ax);
  float p  = (x >= 0.0f) ? 1.0f / (1.0f + e) : e / (1.0f + e);   // sigmoid
  float sp = fmaxf(x, 0.0f) + log1pf(e);                          // softplus(x)
  float pt = 1.0f - p;          // p_t for label=0
  float f  = 1.0f - pt;         // 1 - p_t (mimic reference rounding)
  float l  = sp * f * f * 0.25f;
  return (p >= 0.5f) ? l * 3.0f : l;                              // fp_mask -> *w
}
__device__ __forceinline__ float pos_loss(float x) {
  float ax = fabsf(x);
  float e  = expf(-ax);
  float p  = (x >= 0.0f) ? 1.0f / (1.0f + e) : e / (1.0f + e);
  float sp = fmaxf(-x, 0.0f) + log1pf(e);                         // softplus(-x)
  float f  = 1.0f - p;                                            // 1 - p_t, p_t = p
  float l  = sp * f * f * 0.75f;
  return (p < 0.5f) ? l * 3.0f : l;                               // fn_mask -> *w
}
__device__ __forceinline__ float loss_from_key(unsigned k) { return neg_loss(pred_from_key(k)); }

// =======================  K1: histogram pass  =======================
constexpr int K1_TPB = 256;
constexpr int K1_SEGS = 8;                                   // blocks per row
constexpr int K1_SEG_ELEMS = N_COLS / K1_SEGS;               // 8192
constexpr int K1_ITERS = K1_SEG_ELEMS / (K1_TPB * 4);        // 8

template <bool STORE_KEYS>
__global__ __launch_bounds__(K1_TPB)
void k1_hist(const float* __restrict__ pred, const float* __restrict__ label,
             int* __restrict__ histCnt, float* __restrict__ histLoss,
             int* __restrict__ numPos, float* __restrict__ SPos,
             unsigned* __restrict__ keys)
{
  __shared__ int   hcnt[2048];
  __shared__ float hloss[2048];
  __shared__ int   wnp[K1_TPB / 64];
  __shared__ float wsp[K1_TPB / 64];
  const int tid = threadIdx.x;
  for (int i = tid; i < 2048; i += K1_TPB) { hcnt[i] = 0; hloss[i] = 0.0f; }
  __syncthreads();

  const int row = blockIdx.x / K1_SEGS;
  const int seg = blockIdx.x % K1_SEGS;
  const size_t base = (size_t)row * N_COLS + (size_t)seg * K1_SEG_ELEMS;
  const float4* p4 = reinterpret_cast<const float4*>(pred + base);
  const float4* l4 = reinterpret_cast<const float4*>(label + base);
  uint4* k4 = STORE_KEYS ? reinterpret_cast<uint4*>(keys + base) : nullptr;

  int npos = 0; float spos = 0.0f;
  for (int it = 0; it < K1_ITERS; ++it) {
    const int vi = it * K1_TPB + tid;
    const float4 pv = p4[vi];
    const float4 lv = l4[vi];
    const float xs[4] = {pv.x, pv.y, pv.z, pv.w};
    const float ys[4] = {lv.x, lv.y, lv.z, lv.w};
    unsigned ks[4];
#pragma unroll
    for (int j = 0; j < 4; ++j) {
      const float x = xs[j];
      if (ys[j] > 0.5f) {            // positive
        npos += 1;
        spos += pos_loss(x);
        ks[j] = 0u;
      } else {                       // negative
        const unsigned key = key_from_pred(x);
        ks[j] = key;
        atomicAdd(&hcnt[key >> 21], 1);
        atomicAdd(&hloss[key >> 21], neg_loss(x));
      }
    }
    if (STORE_KEYS) { uint4 uk; uk.x = ks[0]; uk.y = ks[1]; uk.z = ks[2]; uk.w = ks[3]; k4[vi] = uk; }
  }

  // block reduce npos/spos
#pragma unroll
  for (int off = 32; off > 0; off >>= 1) {
    npos += __shfl_down(npos, off);
    spos += __shfl_down(spos, off);
  }
  const int wid = tid >> 6, lane = tid & 63;
  if (lane == 0) { wnp[wid] = npos; wsp[wid] = spos; }
  __syncthreads();
  if (tid == 0) {
    int tn = 0; float ts = 0.0f;
    for (int i = 0; i < K1_TPB / 64; ++i) { tn += wnp[i]; ts += wsp[i]; }
    atomicAdd(&numPos[row], tn);
    unsafeAtomicAdd(&SPos[row], ts);
  }
  __syncthreads();
  for (int i = tid; i < 2048; i += K1_TPB) {
    if (hcnt[i]) {
      atomicAdd(&histCnt[row * 2048 + i], hcnt[i]);
      unsafeAtomicAdd(&histLoss[row * 2048 + i], hloss[i]);
    }
  }
}

// =======================  K2: per-row radix select  =======================
constexpr int K2_TPB = 1024;

// in-place inclusive suffix scan over (c,l)[0..M), M <= 2*blockDim.x
__device__ void suffix_scan(int* c, float* l, int M) {
  const int T = blockDim.x;
  const int i0 = threadIdx.x, i1 = threadIdx.x + T;
  for (int d = 1; d < M; d <<= 1) {
    int vi0 = 0, vi1 = 0; float vf0 = 0.0f, vf1 = 0.0f;
    const bool h0 = i0 < M, h1 = i1 < M;
    if (h0) { vi0 = c[i0] + ((i0 + d < M) ? c[i0 + d] : 0);
              vf0 = l[i0] + ((i0 + d < M) ? l[i0 + d] : 0.0f); }
    if (h1) { vi1 = c[i1] + ((i1 + d < M) ? c[i1 + d] : 0);
              vf1 = l[i1] + ((i1 + d < M) ? l[i1 + d] : 0.0f); }
    __syncthreads();
    if (h0) { c[i0] = vi0; l[i0] = vf0; }
    if (h1) { c[i1] = vi1; l[i1] = vf1; }
    __syncthreads();
  }
}

// max b in [0,M) with scanned[b] >= r (qualifying set is a prefix)
__device__ int find_cut(const int* sc, int M, int r, int* ctrl) {
  __syncthreads();
  if (threadIdx.x == 0) *ctrl = -1;
  __syncthreads();
  int loc = -1;
  for (int i = threadIdx.x; i < M; i += blockDim.x)
    if (sc[i] >= r) loc = i;          // i increasing -> loc ends as local max
  if (loc >= 0) atomicMax(ctrl, loc);
  __syncthreads();
  return *ctrl;
}

template <bool USE_KEYS>
__device__ void stream_filter(const float* __restrict__ pred, const float* __restrict__ label,
                              const unsigned* __restrict__ keys, int row, int b1, int b2,
                              int* hcnt, float* hloss, unsigned* list, int* listCnt)
{
  const size_t base = (size_t)row * N_COLS;
  const int tid = threadIdx.x;

  auto handle = [&](unsigned key) {
    if ((int)(key >> 21) != b1) return;
    if (b2 < 0) {                       // level-2 mode: build hist of bits[20:10] + candidate list
      const int idx = atomicAdd(listCnt, 1);
      if (idx < LIST_CAP) list[idx] = key;
      const int b = (key >> 10) & 0x7FF;
      atomicAdd(&hcnt[b], 1);
      atomicAdd(&hloss[b], loss_from_key(key));
    } else {                            // level-3 fallback mode: bits[9:0]
      if ((int)((key >> 10) & 0x7FF) != b2) return;
      const int b = key & 0x3FF;
      atomicAdd(&hcnt[b], 1);
      atomicAdd(&hloss[b], loss_from_key(key));
    }
  };

  if (USE_KEYS) {
    const uint4* k4 = reinterpret_cast<const uint4*>(keys + base);
    for (int it = 0; it < N_COLS / (K2_TPB * 4); ++it) {
      const uint4 kv = k4[it * K2_TPB + tid];
      const unsigned ks[4] = {kv.x, kv.y, kv.z, kv.w};
#pragma unroll
      for (int j = 0; j < 4; ++j) {
        const unsigned key = ks[j];
        if (key == 0u) continue;        // positives stored as 0
        handle(key);
      }
    }
  } else {
    const float4* p4 = reinterpret_cast<const float4*>(pred + base);
    const float4* l4 = reinterpret_cast<const float4*>(label + base);
    for (int it = 0; it < N_COLS / (K2_TPB * 4); ++it) {
      const float4 pv = p4[it * K2_TPB + tid];
      const float4 lv = l4[it * K2_TPB + tid];
      const float xs[4] = {pv.x, pv.y, pv.z, pv.w};
      const float ys[4] = {lv.x, lv.y, lv.z, lv.w};
#pragma unroll
      for (int j = 0; j < 4; ++j) {
        if (ys[j] > 0.5f) continue;     // skip positives
        handle(key_from_pred(xs[j]));
      }
    }
  }
}

template <bool USE_KEYS>
__global__ __launch_bounds__(K2_TPB)
void k2_select(const float* __restrict__ pred, const float* __restrict__ label,
               const unsigned* __restrict__ keys,
               const int* __restrict__ histCnt, const float* __restrict__ histLoss,
               const int* __restrict__ numPos, const float* __restrict__ SPos,
               double* __restrict__ rowS, int* __restrict__ rowDen)
{
  __shared__ int      s_cnt[2048];
  __shared__ float    s_loss[2048];
  __shared__ int      sc_cnt[1024];
  __shared__ float    sc_loss[1024];
  __shared__ unsigned s_list[LIST_CAP];
  __shared__ int      s_listCnt;
  __shared__ int      s_ctrl;

  const int tid = threadIdx.x;
  const int row = blockIdx.x;
  const int np = numPos[row];
  const int nneg = N_COLS - np;
  const int k = (3 * np < nneg) ? 3 * np : nneg;
  if (k <= 0) {
    if (tid == 0) { rowS[row] = (double)SPos[row]; rowDen[row] = np; }
    return;
  }

  // ---- level 1: coarse bin from global histogram ----
  for (int i = tid; i < 2048; i += K2_TPB) {
    s_cnt[i]  = histCnt[row * 2048 + i];
    s_loss[i] = histLoss[row * 2048 + i];
  }
  __syncthreads();
  suffix_scan(s_cnt, s_loss, 2048);
  const int b1 = find_cut(s_cnt, 2048, k, &s_ctrl);
  const int r1 = k - ((b1 + 1 < 2048) ? s_cnt[b1 + 1] : 0);
  float S = (b1 + 1 < 2048) ? s_loss[b1 + 1] : 0.0f;   // loss of all bins fully above cutoff
  __syncthreads();

  // ---- level 2: stream candidates of bin b1, hist bits[20:10] ----
  for (int i = tid; i < 2048; i += K2_TPB) { s_cnt[i] = 0; s_loss[i] = 0.0f; }
  if (tid == 0) s_listCnt = 0;
  __syncthreads();
  stream_filter<USE_KEYS>(pred, label, keys, row, b1, -1, s_cnt, s_loss, s_list, &s_listCnt);
  __syncthreads();
  const int listTotal = s_listCnt;
  suffix_scan(s_cnt, s_loss, 2048);
  const int b2 = find_cut(s_cnt, 2048, r1, &s_ctrl);
  const int r2 = r1 - ((b2 + 1 < 2048) ? s_cnt[b2 + 1] : 0);
  S += (b2 + 1 < 2048) ? s_loss[b2 + 1] : 0.0f;
  __syncthreads();

  // ---- level 3: bits[9:0] from LDS list (or streamed fallback) ----
  for (int i = tid; i < 1024; i += K2_TPB) { s_cnt[i] = 0; s_loss[i] = 0.0f; }
  __syncthreads();
  if (listTotal <= LIST_CAP) {
    for (int i = tid; i < listTotal; i += K2_TPB) {
      const unsigned key = s_list[i];
      if ((int)((key >> 10) & 0x7FF) == b2) {
        atomicAdd(&s_cnt[key & 0x3FF], 1);
        atomicAdd(&s_loss[key & 0x3FF], loss_from_key(key));
      }
    }
  } else {
    stream_filter<USE_KEYS>(pred, label, keys, row, b1, b2, s_cnt, s_loss, nullptr, nullptr);
  }
  __syncthreads();
  for (int i = tid; i < 1024; i += K2_TPB) { sc_cnt[i] = s_cnt[i]; sc_loss[i] = s_loss[i]; }
  __syncthreads();
  suffix_scan(sc_cnt, sc_loss, 1024);
  const int b3 = find_cut(sc_cnt, 1024, r2, &s_ctrl);
  const int r3 = r2 - ((b3 + 1 < 1024) ? sc_cnt[b3 + 1] : 0);
  S += (b3 + 1 < 1024) ? sc_loss[b3 + 1] : 0.0f;
  // ties at exact cutoff key: identical pred -> identical loss
  const float tie = s_loss[b3] / (float)s_cnt[b3];
  S += (float)r3 * tie;

  if (tid == 0) {
    rowS[row] = (double)S + (double)SPos[row];
    rowDen[row] = np + k;
  }
}

// =======================  K3: final reduction  =======================
__global__ __launch_bounds__(B_ROWS)
void k3_final(const double* __restrict__ rowS, const int* __restrict__ rowDen,
              float* __restrict__ out)
{
  __shared__ double sd[B_ROWS];
  __shared__ long long si[B_ROWS];
  const int t = threadIdx.x;
  sd[t] = rowS[t];
  si[t] = (long long)rowDen[t];
  __syncthreads();
  if (t == 0) {
    double s = 0.0; long long d = 0;
    for (int i = 0; i < B_ROWS; ++i) { s += sd[i]; d += si[i]; }
    out[0] = (float)(s / (double)d);
  }
}

// =======================  host launcher  =======================
extern "C" void kernel_launch(void* const* d_in, const int* in_sizes, int n_in,
                              void* d_out, int out_size, void* d_ws, size_t ws_size,
                              hipStream_t stream)
{
  const float* pred  = (const float*)d_in[0];
  const float* label = (const float*)d_in[1];
  float* out = (float*)d_out;
  char* ws = (char*)d_ws;

  int*      histCnt  = (int*)(ws + OFF_HISTCNT);
  float*    histLoss = (float*)(ws + OFF_HISTLOSS);
  int*      numPos   = (int*)(ws + OFF_NUMPOS);
  float*    SPos     = (float*)(ws + OFF_SPOS);
  double*   rowS     = (double*)(ws + OFF_ROWS);
  int*      rowDen   = (int*)(ws + OFF_ROWDEN);
  unsigned* keys     = (unsigned*)(ws + OFF_KEYS);

  const bool useKeys = ws_size >= OFF_KEYS + (size_t)B_ROWS * N_COLS * sizeof(unsigned);

  hipMemsetAsync(ws, 0, ZERO_BYTES, stream);

  const dim3 g1(B_ROWS * K1_SEGS), t1(K1_TPB);
  const dim3 g2(B_ROWS), t2(K2_TPB);
  if (useKeys) {
    k1_hist<true><<<g1, t1, 0, stream>>>(pred, label, histCnt, histLoss, numPos, SPos, keys);
    k2_select<true><<<g2, t2, 0, stream>>>(pred, label, keys, histCnt, histLoss, numPos, SPos, rowS, rowDen);
  } else {
    k1_hist<false><<<g1, t1, 0, stream>>>(pred, label, histCnt, histLoss, numPos, SPos, nullptr);
    k2_select<false><<<g2, t2, 0, stream>>>(pred, label, nullptr, histCnt, histLoss, numPos, SPos, rowS, rowDen);
  }
  k3_final<<<dim3(1), dim3(B_ROWS), 0, stream>>>(rowS, rowDen, out);
}